// Round 9
// baseline (49323.569 us; speedup 1.0000x reference)
//
#include <hip/hip_runtime.h>
#include <cstddef>

#define B_SZ   16
#define T_SZ   4096
#define D_SZ   512
#define NSLOT  64
#define NW     16          // d-slices (WGs per batch)
#define RPW    32          // rows per slice
#define NC     4           // chains (batches) per WG — pipelined to hide sync RT
#define TP     36          // LDS tape row stride (floats; 144B, 16B-aligned)
#define SCALE  0.044194173824159216f   // 1/sqrt(512)

// ---- cross-WG exchange: self-tagged (float,tag) 8B pairs, relaxed agent
// ---- atomics only (no fences — see R5). Producers zero their own slots at
// ---- start; equality-poll is replay-safe (monotone per-address history).
// ---- Overwrite-before-consume is impossible: publishing tag t+2 requires the
// ---- producer's tag-t+1 polls to have succeeded for ALL slices first.
__device__ __align__(8) unsigned long long g_pb[B_SZ * NW * NSLOT]; // score partials [b][w][slot]
__device__ __align__(8) unsigned long long g_hb[B_SZ * D_SZ];      // h, flat [b][d]

#define AL(p)    __hip_atomic_load((p),  __ATOMIC_RELAXED, __HIP_MEMORY_SCOPE_AGENT)
#define AS(p,v)  __hip_atomic_store((p), (v), __ATOMIC_RELAXED, __HIP_MEMORY_SCOPE_AGENT)

__device__ __forceinline__ unsigned long long pk(float v, unsigned tag) {
    return ((unsigned long long)tag << 32) | (unsigned long long)__float_as_uint(v);
}
__device__ __forceinline__ float lo(unsigned long long v) {
    return __uint_as_float((unsigned)v);
}
// keep a value in a VGPR: opaque identity the compiler can't rematerialize
#define PIN(x) asm volatile("" : "+v"(x))
#define PIN4(v) do { PIN((v).x); PIN((v).y); PIN((v).z); PIN((v).w); } while (0)

// ---------------------------------------------------------------------------
// Kernel 1: xw[b][t][d] = x[b][t][:] . W_x[d][:] + b_h[d]  -> h_work_out region
// ---------------------------------------------------------------------------
__global__ __launch_bounds__(256)
void xw_gemm_kernel(const float* __restrict__ X, const float* __restrict__ Wx,
                    const float* __restrict__ bh, float* __restrict__ out)
{
    __shared__ float As[16][68];
    __shared__ float Bs[16][68];
    const int m0 = blockIdx.x * 64;
    const int n0 = blockIdx.y * 64;
    const int tid = threadIdx.x;
    const int tr = tid >> 4, tc = tid & 15;
    const int lrow = tid >> 2;
    const int lkk  = (tid & 3) * 4;

    float acc[4][4] = {};

    for (int k0 = 0; k0 < D_SZ; k0 += 16) {
        float4 av = *(const float4*)(X  + (size_t)(m0 + lrow) * D_SZ + k0 + lkk);
        float4 bv = *(const float4*)(Wx + (size_t)(n0 + lrow) * D_SZ + k0 + lkk);
        As[lkk+0][lrow] = av.x; As[lkk+1][lrow] = av.y;
        As[lkk+2][lrow] = av.z; As[lkk+3][lrow] = av.w;
        Bs[lkk+0][lrow] = bv.x; Bs[lkk+1][lrow] = bv.y;
        Bs[lkk+2][lrow] = bv.z; Bs[lkk+3][lrow] = bv.w;
        __syncthreads();
        #pragma unroll
        for (int kk = 0; kk < 16; ++kk) {
            float a[4], b[4];
            #pragma unroll
            for (int i = 0; i < 4; ++i) a[i] = As[kk][tr*4+i];
            #pragma unroll
            for (int j = 0; j < 4; ++j) b[j] = Bs[kk][tc*4+j];
            #pragma unroll
            for (int i = 0; i < 4; ++i)
                #pragma unroll
                for (int j = 0; j < 4; ++j)
                    acc[i][j] = fmaf(a[i], b[j], acc[i][j]);
        }
        __syncthreads();
    }
    #pragma unroll
    for (int i = 0; i < 4; ++i) {
        const int m = m0 + tr*4 + i;
        const int n = n0 + tc*4;
        float4 o;
        o.x = acc[i][0] + bh[n+0];
        o.y = acc[i][1] + bh[n+1];
        o.z = acc[i][2] + bh[n+2];
        o.w = acc[i][3] + bh[n+3];
        *(float4*)(out + (size_t)m * D_SZ + n) = o;
    }
}

// ---------------------------------------------------------------------------
// Kernel 2: d-sliced recurrence, 4 chains per WG pipelined so the MALL sync
// round-trips of chain c hide behind the other 3 chains' compute.
// Grid = 64 WGs: w = blk&15 (slice), g = blk>>4 (batch group of 4).
// ---------------------------------------------------------------------------
__global__ __launch_bounds__(256, 1)
void recurrence_mw(const float* __restrict__ tape0, const float* __restrict__ h0,
                   const float* __restrict__ W_h, const float* __restrict__ W_w,
                   float* __restrict__ out)
{
    __shared__ __align__(16) float tp[NC][NSLOT][TP];  // 36,864 B
    __shared__ __align__(16) float hh[NC][D_SZ];       //  8,192 B
    __shared__ float scr[NC][NSLOT];                   //  1,024 B
    __shared__ float es[NC][NSLOT];                    //  1,024 B
    __shared__ float zmv[NC][RPW];                     //    512 B
    __shared__ float rp8[NC][8][RPW];                  //  4,096 B
    __shared__ float sml[NC];
    __shared__ float xwc[NC][RPW];                     //    512 B

    const int blk = blockIdx.x;
    const int w   = blk & 15;
    const int g   = blk >> 4;
    const int R0  = w * RPW;
    const int tid = threadIdx.x;
    const int g16 = tid >> 4, sj = tid & 15;   // matvec: rows (g16, g16+16), 16 k-lanes
    const int sA  = tid >> 2, qA = tid & 3;    // scores: 4 threads per slot
    const int sg  = tid >> 5, jB = tid & 31;   // read-partials: 8 slot-groups

    // ---- zero own exchange slots (replay safety) ----
    #pragma unroll
    for (int c = 0; c < NC; ++c) {
        const int b = g * NC + c;
        if (tid < NSLOT) AS(&g_pb[((size_t)b * NW + w) * NSLOT + tid], 0ULL);
        if (tid < RPW)   AS(&g_hb[(size_t)b * D_SZ + R0 + tid], 0ULL);
    }

    // ---- weight slices -> registers, pinned against rematerialization ----
    float4 wh0[8], wh1[8], ww0[8], ww1[8];
    {
        const float* a0 = W_h + (size_t)(R0 + g16)      * D_SZ + 4 * sj;
        const float* a1 = W_h + (size_t)(R0 + g16 + 16) * D_SZ + 4 * sj;
        const float* b0 = W_w + (size_t)(R0 + g16)      * D_SZ + 4 * sj;
        const float* b1 = W_w + (size_t)(R0 + g16 + 16) * D_SZ + 4 * sj;
        #pragma unroll
        for (int i = 0; i < 8; ++i) {
            wh0[i] = *(const float4*)(a0 + 64 * i);  PIN4(wh0[i]);
            wh1[i] = *(const float4*)(a1 + 64 * i);  PIN4(wh1[i]);
            ww0[i] = *(const float4*)(b0 + 64 * i);  PIN4(ww0[i]);
            ww1[i] = *(const float4*)(b1 + 64 * i);  PIN4(ww1[i]);
        }
    }

    // ---- stage tape slices + h0 for the 4 chains ----
    for (int c = 0; c < NC; ++c) {
        const int b = g * NC + c;
        for (int i = tid; i < NSLOT * RPW; i += 256) {
            const int s = i >> 5, j = i & 31;
            tp[c][s][j] = tape0[((size_t)b * NSLOT + s) * D_SZ + R0 + j];
        }
        for (int i = tid; i < D_SZ; i += 256) hh[c][i] = h0[(size_t)b * D_SZ + i];
    }
    __syncthreads();   // drains the zeroing stores before any publish

    for (int t = 0; t < T_SZ; ++t) {
        const unsigned tgP = (unsigned)(t + 1);
        const int sp = (t - 1) & 63;   // slot written by step t-1 (valid t>0)

        // ============ H1(c): poll h_t; tape write; zm; publish partials ======
        #pragma unroll 1
        for (int c = 0; c < NC; ++c) {
            const int b = g * NC + c;
            float* ob = out + (size_t)b * T_SZ * D_SZ;
            if (tid < RPW) xwc[c][tid] = ob[(size_t)t * D_SZ + R0 + tid];
            if (t > 0) {
                const unsigned long long* hb = &g_hb[(size_t)b * D_SZ + 2 * tid];
                unsigned long long v0, v1;
                for (;;) {
                    v0 = AL(hb); v1 = AL(hb + 1);
                    if ((unsigned)(v0 >> 32) == tgP && (unsigned)(v1 >> 32) == tgP) break;
                    __builtin_amdgcn_s_sleep(1);
                }
                hh[c][2 * tid]     = lo(v0);
                hh[c][2 * tid + 1] = lo(v1);
            }
            __syncthreads();

            // fused matvec: zmv = W_h.h_t ; tape slot sp = W_w.h_t (one hh pass)
            {
                float z0 = 0.f, z1 = 0.f, y0 = 0.f, y1 = 0.f;
                #pragma unroll
                for (int i = 0; i < 8; ++i) {
                    float4 hr = *(const float4*)&hh[c][4 * sj + 64 * i];
                    z0 = fmaf(wh0[i].x, hr.x, z0); z0 = fmaf(wh0[i].y, hr.y, z0);
                    z0 = fmaf(wh0[i].z, hr.z, z0); z0 = fmaf(wh0[i].w, hr.w, z0);
                    z1 = fmaf(wh1[i].x, hr.x, z1); z1 = fmaf(wh1[i].y, hr.y, z1);
                    z1 = fmaf(wh1[i].z, hr.z, z1); z1 = fmaf(wh1[i].w, hr.w, z1);
                    y0 = fmaf(ww0[i].x, hr.x, y0); y0 = fmaf(ww0[i].y, hr.y, y0);
                    y0 = fmaf(ww0[i].z, hr.z, y0); y0 = fmaf(ww0[i].w, hr.w, y0);
                    y1 = fmaf(ww1[i].x, hr.x, y1); y1 = fmaf(ww1[i].y, hr.y, y1);
                    y1 = fmaf(ww1[i].z, hr.z, y1); y1 = fmaf(ww1[i].w, hr.w, y1);
                }
                #pragma unroll
                for (int o = 1; o <= 8; o <<= 1) {
                    z0 += __shfl_xor(z0, o); z1 += __shfl_xor(z1, o);
                    y0 += __shfl_xor(y0, o); y1 += __shfl_xor(y1, o);
                }
                if (sj == 0) {
                    zmv[c][g16] = z0; zmv[c][g16 + 16] = z1;
                    if (t > 0) { tp[c][sp][g16] = y0; tp[c][sp][g16 + 16] = y1; }
                }
            }
            __syncthreads();

            // score partials over the UP-TO-DATE tape; publish straight to MALL
            {
                const float* trow = &tp[c][sA][8 * qA];
                float4 t0 = *(const float4*)trow;
                float4 t1 = *(const float4*)(trow + 4);
                float4 ha = *(const float4*)&hh[c][R0 + 8 * qA];
                float4 hb4 = *(const float4*)&hh[c][R0 + 8 * qA + 4];
                float pp = t0.x*ha.x + t0.y*ha.y + t0.z*ha.z + t0.w*ha.w
                         + t1.x*hb4.x + t1.y*hb4.y + t1.z*hb4.z + t1.w*hb4.w;
                pp += __shfl_xor(pp, 1);
                pp += __shfl_xor(pp, 2);
                if (qA == 0)
                    AS(&g_pb[((size_t)b * NW + w) * NSLOT + sA], pk(pp, tgP));
            }
            // no trailing barrier: next chain touches disjoint buffers
        }

        // ============ H2(c): poll partials; softmax; read; tanh; publish h ===
        #pragma unroll 1
        for (int c = 0; c < NC; ++c) {
            const int b = g * NC + c;
            float* ob = out + (size_t)b * T_SZ * D_SZ;
            {
                const unsigned long long* pb =
                    &g_pb[((size_t)b * NW + qA * 4) * NSLOT + sA];
                unsigned long long p0, p1, p2, p3;
                for (;;) {
                    p0 = AL(pb);             p1 = AL(pb + NSLOT);
                    p2 = AL(pb + 2 * NSLOT); p3 = AL(pb + 3 * NSLOT);
                    if ((unsigned)(p0 >> 32) == tgP && (unsigned)(p1 >> 32) == tgP &&
                        (unsigned)(p2 >> 32) == tgP && (unsigned)(p3 >> 32) == tgP) break;
                    __builtin_amdgcn_s_sleep(1);
                }
                float s4 = lo(p0) + lo(p1) + lo(p2) + lo(p3);
                s4 += __shfl_xor(s4, 1);
                s4 += __shfl_xor(s4, 2);
                if (qA == 0) scr[c][sA] = s4 * SCALE;
            }
            __syncthreads();

            if (tid < 64) {
                const float v = scr[c][tid];
                float m = v;
                #pragma unroll
                for (int o = 32; o; o >>= 1) m = fmaxf(m, __shfl_xor(m, o));
                const float e = __expf(v - m);
                float s = e;
                #pragma unroll
                for (int o = 32; o; o >>= 1) s += __shfl_xor(s, o);
                es[c][tid] = e;
                if (tid == 0) sml[c] = s;
            }
            __syncthreads();

            {
                float acc = 0.f;
                #pragma unroll
                for (int s8 = 0; s8 < 8; ++s8)
                    acc = fmaf(es[c][sg * 8 + s8], tp[c][sg * 8 + s8][jB], acc);
                rp8[c][sg][jB] = acc;
            }
            __syncthreads();

            if (tid < RPW) {
                const float rr = rp8[c][0][tid] + rp8[c][1][tid] + rp8[c][2][tid]
                               + rp8[c][3][tid] + rp8[c][4][tid] + rp8[c][5][tid]
                               + rp8[c][6][tid] + rp8[c][7][tid];
                const float rd = rr / sml[c];
                const float hn = tanhf(zmv[c][tid] + rd + xwc[c][tid]);
                AS(&g_hb[(size_t)b * D_SZ + R0 + tid], pk(hn, (unsigned)(t + 2)));
                ob[(size_t)t * D_SZ + R0 + tid] = hn;
            }
            // no trailing barrier: next chain touches disjoint buffers
        }
    }

    // ---- epilogue per chain: poll h_T, final slot-63 write, dump state ----
    for (int c = 0; c < NC; ++c) {
        const int b = g * NC + c;
        {
            const unsigned long long* hb = &g_hb[(size_t)b * D_SZ + 2 * tid];
            const unsigned tgF = (unsigned)(T_SZ + 1);
            unsigned long long v0, v1;
            for (;;) {
                v0 = AL(hb); v1 = AL(hb + 1);
                if ((unsigned)(v0 >> 32) == tgF && (unsigned)(v1 >> 32) == tgF) break;
                __builtin_amdgcn_s_sleep(1);
            }
            hh[c][2 * tid]     = lo(v0);
            hh[c][2 * tid + 1] = lo(v1);
        }
        __syncthreads();
        {
            float y0 = 0.f, y1 = 0.f;
            #pragma unroll
            for (int i = 0; i < 8; ++i) {
                float4 hr = *(const float4*)&hh[c][4 * sj + 64 * i];
                y0 = fmaf(ww0[i].x, hr.x, y0); y0 = fmaf(ww0[i].y, hr.y, y0);
                y0 = fmaf(ww0[i].z, hr.z, y0); y0 = fmaf(ww0[i].w, hr.w, y0);
                y1 = fmaf(ww1[i].x, hr.x, y1); y1 = fmaf(ww1[i].y, hr.y, y1);
                y1 = fmaf(ww1[i].z, hr.z, y1); y1 = fmaf(ww1[i].w, hr.w, y1);
            }
            #pragma unroll
            for (int o = 1; o <= 8; o <<= 1) {
                y0 += __shfl_xor(y0, o); y1 += __shfl_xor(y1, o);
            }
            if (sj == 0) { tp[c][63][g16] = y0; tp[c][63][g16 + 16] = y1; }
        }
        __syncthreads();
        float* tout = out + (size_t)B_SZ * T_SZ * D_SZ + (size_t)b * NSLOT * D_SZ;
        for (int i = tid; i < NSLOT * RPW; i += 256) {
            const int s = i >> 5, j = i & 31;
            tout[(size_t)s * D_SZ + R0 + j] = tp[c][s][j];
        }
        if (w == 0) {
            float* lout = out + (size_t)B_SZ * T_SZ * D_SZ
                              + (size_t)B_SZ * NSLOT * D_SZ + (size_t)b * D_SZ;
            for (int i = tid; i < D_SZ; i += 256) lout[i] = hh[c][i];
        }
        __syncthreads();
    }
}

// ---------------------------------------------------------------------------
extern "C" void kernel_launch(void* const* d_in, const int* in_sizes, int n_in,
                              void* d_out, int out_size, void* d_ws, size_t ws_size,
                              hipStream_t stream)
{
    const float* x_seq   = (const float*)d_in[0];
    const float* h_tape  = (const float*)d_in[1];
    const float* h_work  = (const float*)d_in[2];
    const float* W_h     = (const float*)d_in[3];
    const float* W_x     = (const float*)d_in[4];
    const float* b_h     = (const float*)d_in[5];
    const float* W_write = (const float*)d_in[6];
    float* out = (float*)d_out;

    dim3 g1(T_SZ * B_SZ / 64, D_SZ / 64);
    xw_gemm_kernel<<<g1, 256, 0, stream>>>(x_seq, W_x, b_h, out);

    recurrence_mw<<<B_SZ * NW / NC, 256, 0, stream>>>(h_tape, h_work, W_h, W_write, out);
}

// Round 10
// 17009.482 us; speedup vs baseline: 2.8998x; 2.8998x over previous
//
#include <hip/hip_runtime.h>
#include <cstddef>

#define B_SZ   16
#define T_SZ   4096
#define D_SZ   512
#define NSLOT  64
#define NW     16          // workgroups (d-slices) per batch
#define RPW    32          // rows per WG slice (D_SZ / NW)
#define TP     36          // LDS tape row stride (floats; 144B, 16B-aligned)
#define SCALE  0.044194173824159216f   // 1/sqrt(512)

typedef float f32x4 __attribute__((ext_vector_type(4)));

// ---- cross-WG exchange: self-tagged (float,tag) 8B pairs (relaxed agent
// ---- atomics, no fences — see R5). Producers zero their own slots at start;
// ---- equality-poll on the tag is replay-safe (monotone per-address history).
__device__ __align__(8) unsigned long long g_pb[B_SZ * NW * NSLOT]; // score partials [b][w][slot]
__device__ __align__(8) unsigned long long g_hb[B_SZ * D_SZ];      // h slices, flat [b][d]
__device__ __align__(8) unsigned long long g_q [B_SZ * NW];        // quadratic partials [b][w]

#define AL(p)    __hip_atomic_load((p),  __ATOMIC_RELAXED, __HIP_MEMORY_SCOPE_AGENT)
#define AS(p,v)  __hip_atomic_store((p), (v), __ATOMIC_RELAXED, __HIP_MEMORY_SCOPE_AGENT)

__device__ __forceinline__ unsigned long long pk(float v, unsigned tag) {
    return ((unsigned long long)tag << 32) | (unsigned long long)__float_as_uint(v);
}
__device__ __forceinline__ float lo(unsigned long long v) {
    return __uint_as_float((unsigned)v);
}

// Non-rematerializable 16B load: value is produced by volatile asm, so the
// compiler CANNOT re-execute it and must keep the result in VGPRs for its
// whole live range. This is the fix for the silent per-step L2 weight reload
// (R7-R9: VGPR_Count 96..100 < the 128 needed; ~512KB/WG/step L2 traffic).
__device__ __forceinline__ f32x4 load16_pin(const float* p) {
    f32x4 v;
    asm volatile("global_load_dwordx4 %0, %1, off" : "=v"(v) : "v"(p));
    return v;
}

// ---------------------------------------------------------------------------
// Kernel 1: xw[b][t][d] = x[b][t][:] . W_x[d][:] + b_h[d]  -> h_work_out region
// ---------------------------------------------------------------------------
__global__ __launch_bounds__(256)
void xw_gemm_kernel(const float* __restrict__ X, const float* __restrict__ Wx,
                    const float* __restrict__ bh, float* __restrict__ out)
{
    __shared__ float As[16][68];
    __shared__ float Bs[16][68];
    const int m0 = blockIdx.x * 64;
    const int n0 = blockIdx.y * 64;
    const int tid = threadIdx.x;
    const int tr = tid >> 4, tc = tid & 15;
    const int lrow = tid >> 2;
    const int lkk  = (tid & 3) * 4;

    float acc[4][4] = {};

    for (int k0 = 0; k0 < D_SZ; k0 += 16) {
        float4 av = *(const float4*)(X  + (size_t)(m0 + lrow) * D_SZ + k0 + lkk);
        float4 bv = *(const float4*)(Wx + (size_t)(n0 + lrow) * D_SZ + k0 + lkk);
        As[lkk+0][lrow] = av.x; As[lkk+1][lrow] = av.y;
        As[lkk+2][lrow] = av.z; As[lkk+3][lrow] = av.w;
        Bs[lkk+0][lrow] = bv.x; Bs[lkk+1][lrow] = bv.y;
        Bs[lkk+2][lrow] = bv.z; Bs[lkk+3][lrow] = bv.w;
        __syncthreads();
        #pragma unroll
        for (int kk = 0; kk < 16; ++kk) {
            float a[4], b[4];
            #pragma unroll
            for (int i = 0; i < 4; ++i) a[i] = As[kk][tr*4+i];
            #pragma unroll
            for (int j = 0; j < 4; ++j) b[j] = Bs[kk][tc*4+j];
            #pragma unroll
            for (int i = 0; i < 4; ++i)
                #pragma unroll
                for (int j = 0; j < 4; ++j)
                    acc[i][j] = fmaf(a[i], b[j], acc[i][j]);
        }
        __syncthreads();
    }
    #pragma unroll
    for (int i = 0; i < 4; ++i) {
        const int m = m0 + tr*4 + i;
        const int n = n0 + tc*4;
        float4 o;
        o.x = acc[i][0] + bh[n+0];
        o.y = acc[i][1] + bh[n+1];
        o.z = acc[i][2] + bh[n+2];
        o.w = acc[i][3] + bh[n+3];
        *(float4*)(out + (size_t)m * D_SZ + n) = o;
    }
}

// ---------------------------------------------------------------------------
// Kernel 2: single-bundle recurrence (R7 structure) with asm-pinned
// register-resident weights.
// ---------------------------------------------------------------------------
__global__ __launch_bounds__(256, 1)
void recurrence_mw(const float* __restrict__ tape0, const float* __restrict__ h0,
                   const float* __restrict__ W_h, const float* __restrict__ W_w,
                   float* __restrict__ out)
{
    __shared__ __align__(16) float tp[NSLOT][TP];  // tape d-slice [slot][32]
    __shared__ __align__(16) float hh[D_SZ];       // full current h
    __shared__ __align__(16) float hno[RPW];       // own h_new slice
    __shared__ float scr[NSLOT];                   // total scores (scaled)
    __shared__ float es[NSLOT];                    // exp(score - m63)
    __shared__ float zmv[RPW];
    __shared__ float rp8[8][RPW];
    __shared__ float sml[2];                       // m63, S63

    const int blk = blockIdx.x;
    const int xcd = blk & 7;
    const int jj0 = blk >> 3;
    const int b   = xcd * 2 + (jj0 & 1);
    const int w   = jj0 >> 1;
    const int R0  = w * RPW;
    const int tid = threadIdx.x;
    const int fb  = b * NW;
    const int g16 = tid >> 4, sj = tid & 15;   // matvec: 16 lanes per row-pair
    const int sA  = tid >> 2, qA = tid & 3;    // partials/poll: 4 threads per slot
    const int sg  = tid >> 5, jB = tid & 31;   // rpA: 8 slot-groups

    // ---- zero own pair slots (replay safety) ----
    if (tid < NSLOT) AS(&g_pb[((size_t)fb + w) * NSLOT + tid], 0ULL);
    if (tid < RPW)   AS(&g_hb[(size_t)b * D_SZ + R0 + tid], 0ULL);
    if (tid == 0)    AS(&g_q[fb + w], 0ULL);

    // ---- weight slices into registers, NON-rematerializable (asm loads) ----
    f32x4 wh0[8], wh1[8], ww0[8], ww1[8];
    {
        const float* a0 = W_h + (size_t)(R0 + g16)      * D_SZ + 4 * sj;
        const float* a1 = W_h + (size_t)(R0 + g16 + 16) * D_SZ + 4 * sj;
        const float* b0 = W_w + (size_t)(R0 + g16)      * D_SZ + 4 * sj;
        const float* b1 = W_w + (size_t)(R0 + g16 + 16) * D_SZ + 4 * sj;
        #pragma unroll
        for (int i = 0; i < 8; ++i) {
            wh0[i] = load16_pin(a0 + 64 * i);
            wh1[i] = load16_pin(a1 + 64 * i);
            ww0[i] = load16_pin(b0 + 64 * i);
            ww1[i] = load16_pin(b1 + 64 * i);
        }
        asm volatile("s_waitcnt vmcnt(0)" ::: "memory");
    }

    // ---- stage tape d-slice + full h0 ----
    for (int i = tid; i < NSLOT * RPW; i += 256) {
        const int s = i >> 5, j = i & 31;
        tp[s][j] = tape0[((size_t)b * NSLOT + s) * D_SZ + R0 + j];
    }
    for (int i = tid; i < D_SZ; i += 256) hh[i] = h0[(size_t)b * D_SZ + i];
    __syncthreads();

    float* outb = out + (size_t)b * T_SZ * D_SZ;

    // ---- prologue: publish bundle serving step 0 (tag 1) ----
    if (tid < RPW) {
        hno[tid] = hh[R0 + tid];
        AS(&g_hb[(size_t)b * D_SZ + R0 + tid], pk(hh[R0 + tid], 1u));
    }
    __syncthreads();
    {
        const float* trow = &tp[sA][8 * qA];
        float4 t0 = *(const float4*)trow;
        float4 t1 = *(const float4*)(trow + 4);
        float4 h0v = *(const float4*)&hno[8 * qA];
        float4 h1v = *(const float4*)&hno[8 * qA + 4];
        float pp = t0.x*h0v.x + t0.y*h0v.y + t0.z*h0v.z + t0.w*h0v.w
                 + t1.x*h1v.x + t1.y*h1v.y + t1.z*h1v.z + t1.w*h1v.w;
        pp += __shfl_xor(pp, 1);
        pp += __shfl_xor(pp, 2);
        if (qA == 0) AS(&g_pb[((size_t)fb + w) * NSLOT + sA], pk(pp, 1u));
    }

    for (int t = 0; t < T_SZ; ++t) {
        const unsigned tgB = (unsigned)(t + 1);
        const int sp = (t - 1) & 63;   // slot pending update (valid when t>0)

        // ---- P0: main poll (score partials x4 + h pairs x2 per thread) ----
        float xwv = 0.f;
        if (tid < RPW) xwv = outb[(size_t)t * D_SZ + R0 + tid];
        {
            const unsigned long long* pb = &g_pb[((size_t)fb + qA * 4) * NSLOT + sA];
            const unsigned long long* hb = &g_hb[(size_t)b * D_SZ + 2 * tid];
            unsigned long long p0, p1, p2, p3, v0, v1;
            for (;;) {
                p0 = AL(pb);              p1 = AL(pb + NSLOT);
                p2 = AL(pb + 2 * NSLOT);  p3 = AL(pb + 3 * NSLOT);
                v0 = AL(hb);              v1 = AL(hb + 1);
                if ((unsigned)(p0 >> 32) == tgB && (unsigned)(p1 >> 32) == tgB &&
                    (unsigned)(p2 >> 32) == tgB && (unsigned)(p3 >> 32) == tgB &&
                    (unsigned)(v0 >> 32) == tgB && (unsigned)(v1 >> 32) == tgB) break;
                __builtin_amdgcn_s_sleep(1);
            }
            float s4 = lo(p0) + lo(p1) + lo(p2) + lo(p3);
            s4 += __shfl_xor(s4, 1);
            s4 += __shfl_xor(s4, 2);
            if (qA == 0) scr[sA] = s4 * SCALE;
            hh[2 * tid]     = lo(v0);
            hh[2 * tid + 1] = lo(v1);
        }
        __syncthreads();

        // ---- P1: fused matvec: zm (W_h) + w_vec (W_w) share one hh pass ----
        {
            float z0 = 0.f, z1 = 0.f, v0 = 0.f, v1 = 0.f;
            #pragma unroll
            for (int i = 0; i < 8; ++i) {
                float4 hr = *(const float4*)&hh[4 * sj + 64 * i];
                z0 = fmaf(wh0[i].x, hr.x, z0); z0 = fmaf(wh0[i].y, hr.y, z0);
                z0 = fmaf(wh0[i].z, hr.z, z0); z0 = fmaf(wh0[i].w, hr.w, z0);
                z1 = fmaf(wh1[i].x, hr.x, z1); z1 = fmaf(wh1[i].y, hr.y, z1);
                z1 = fmaf(wh1[i].z, hr.z, z1); z1 = fmaf(wh1[i].w, hr.w, z1);
                v0 = fmaf(ww0[i].x, hr.x, v0); v0 = fmaf(ww0[i].y, hr.y, v0);
                v0 = fmaf(ww0[i].z, hr.z, v0); v0 = fmaf(ww0[i].w, hr.w, v0);
                v1 = fmaf(ww1[i].x, hr.x, v1); v1 = fmaf(ww1[i].y, hr.y, v1);
                v1 = fmaf(ww1[i].z, hr.z, v1); v1 = fmaf(ww1[i].w, hr.w, v1);
            }
            #pragma unroll
            for (int o = 1; o <= 8; o <<= 1) {
                z0 += __shfl_xor(z0, o); z1 += __shfl_xor(z1, o);
                v0 += __shfl_xor(v0, o); v1 += __shfl_xor(v1, o);
            }
            if (sj == 0) {
                zmv[g16] = z0; zmv[g16 + 16] = z1;
                if (t > 0) { tp[sp][g16] = v0; tp[sp][g16 + 16] = v1; }
            }
        }
        __syncthreads();

        // ---- P2: softmax over 63 (wave0) || q_g compute+publish (tid 64..95) ----
        if (tid < 64) {
            const float v = (t > 0 && tid == sp) ? -3.0e38f : scr[tid];
            float m = v;
            #pragma unroll
            for (int o = 32; o; o >>= 1) m = fmaxf(m, __shfl_xor(m, o));
            const float e = __expf(v - m);
            float s = e;
            #pragma unroll
            for (int o = 32; o; o >>= 1) s += __shfl_xor(s, o);
            es[tid] = e;
            if (tid == 0) { sml[0] = m; sml[1] = s; }
        } else if (tid < 96 && t > 0) {
            const int ld = tid - 64;                   // 0..31
            float qp = tp[sp][ld] * hh[R0 + ld];
            #pragma unroll
            for (int o = 1; o <= 16; o <<= 1) qp += __shfl_xor(qp, o);
            if (ld == 0) AS(&g_q[fb + w], pk(qp, tgB));
        }
        __syncthreads();

        // ---- P3: rpA partials (es[sp]==0 excludes the pending slot) ----
        {
            float acc = 0.f;
            #pragma unroll
            for (int s8 = 0; s8 < 8; ++s8)
                acc = fmaf(es[sg * 8 + s8], tp[sg * 8 + s8][jB], acc);
            rp8[sg][jB] = acc;
        }
        __syncthreads();

        // ---- P4: combine (tid<32): q-poll, read, tanh, publish h ----
        if (tid < RPW) {
            const float rr = rp8[0][tid] + rp8[1][tid] + rp8[2][tid] + rp8[3][tid]
                           + rp8[4][tid] + rp8[5][tid] + rp8[6][tid] + rp8[7][tid];
            float rd;
            if (t > 0) {
                const unsigned long long* qp_ = &g_q[fb + (tid & 15)];
                unsigned long long qv;
                for (;;) {
                    qv = AL(qp_);
                    if ((unsigned)(qv >> 32) == tgB) break;
                    __builtin_amdgcn_s_sleep(1);
                }
                float qs = lo(qv);
                qs += __shfl_xor(qs, 1); qs += __shfl_xor(qs, 2);
                qs += __shfl_xor(qs, 4); qs += __shfl_xor(qs, 8);
                const float esig = __expf(qs * SCALE - sml[0]);
                rd = (rr + esig * tp[sp][tid]) / (sml[1] + esig);
            } else {
                rd = rr / sml[1];
            }
            const float hn = tanhf(zmv[tid] + rd + xwv);
            outb[(size_t)t * D_SZ + R0 + tid] = hn;
            AS(&g_hb[(size_t)b * D_SZ + R0 + tid], pk(hn, (unsigned)(t + 2)));
            hno[tid] = hn;
        }
        __syncthreads();

        // ---- P5: score partials for step t+1 (all 64 slots) ----
        {
            const float* trow = &tp[sA][8 * qA];
            float4 t0 = *(const float4*)trow;
            float4 t1 = *(const float4*)(trow + 4);
            float4 h0v = *(const float4*)&hno[8 * qA];
            float4 h1v = *(const float4*)&hno[8 * qA + 4];
            float pp = t0.x*h0v.x + t0.y*h0v.y + t0.z*h0v.z + t0.w*h0v.w
                     + t1.x*h1v.x + t1.y*h1v.y + t1.z*h1v.z + t1.w*h1v.w;
            pp += __shfl_xor(pp, 1);
            pp += __shfl_xor(pp, 2);
            if (qA == 0) AS(&g_pb[((size_t)fb + w) * NSLOT + sA], pk(pp, (unsigned)(t + 2)));
        }
        // no trailing barrier: next P0 touches scr/hh only, ordered by its own barrier
    }

    // ---- epilogue: gather h_T, final slot-63 update, write tape + last h ----
    {
        const unsigned long long* hb = &g_hb[(size_t)b * D_SZ + 2 * tid];
        unsigned long long v0, v1;
        const unsigned tgF = (unsigned)(T_SZ + 1);
        for (;;) {
            v0 = AL(hb); v1 = AL(hb + 1);
            if ((unsigned)(v0 >> 32) == tgF && (unsigned)(v1 >> 32) == tgF) break;
            __builtin_amdgcn_s_sleep(1);
        }
        hh[2 * tid]     = lo(v0);
        hh[2 * tid + 1] = lo(v1);
    }
    __syncthreads();
    {
        float v0 = 0.f, v1 = 0.f;
        #pragma unroll
        for (int i = 0; i < 8; ++i) {
            float4 hr = *(const float4*)&hh[4 * sj + 64 * i];
            v0 = fmaf(ww0[i].x, hr.x, v0); v0 = fmaf(ww0[i].y, hr.y, v0);
            v0 = fmaf(ww0[i].z, hr.z, v0); v0 = fmaf(ww0[i].w, hr.w, v0);
            v1 = fmaf(ww1[i].x, hr.x, v1); v1 = fmaf(ww1[i].y, hr.y, v1);
            v1 = fmaf(ww1[i].z, hr.z, v1); v1 = fmaf(ww1[i].w, hr.w, v1);
        }
        #pragma unroll
        for (int o = 1; o <= 8; o <<= 1) { v0 += __shfl_xor(v0, o); v1 += __shfl_xor(v1, o); }
        if (sj == 0) { tp[63][g16] = v0; tp[63][g16 + 16] = v1; }
    }
    __syncthreads();
    float* tout = out + (size_t)B_SZ * T_SZ * D_SZ + (size_t)b * NSLOT * D_SZ;
    for (int i = tid; i < NSLOT * RPW; i += 256) {
        const int s = i >> 5, j = i & 31;
        tout[(size_t)s * D_SZ + R0 + j] = tp[s][j];
    }
    if (w == 0) {
        float* lout = out + (size_t)B_SZ * T_SZ * D_SZ
                          + (size_t)B_SZ * NSLOT * D_SZ + (size_t)b * D_SZ;
        for (int i = tid; i < D_SZ; i += 256) lout[i] = hh[i];
    }
}

// ---------------------------------------------------------------------------
extern "C" void kernel_launch(void* const* d_in, const int* in_sizes, int n_in,
                              void* d_out, int out_size, void* d_ws, size_t ws_size,
                              hipStream_t stream)
{
    const float* x_seq   = (const float*)d_in[0];
    const float* h_tape  = (const float*)d_in[1];
    const float* h_work  = (const float*)d_in[2];
    const float* W_h     = (const float*)d_in[3];
    const float* W_x     = (const float*)d_in[4];
    const float* b_h     = (const float*)d_in[5];
    const float* W_write = (const float*)d_in[6];
    float* out = (float*)d_out;

    dim3 g1(T_SZ * B_SZ / 64, D_SZ / 64);
    xw_gemm_kernel<<<g1, 256, 0, stream>>>(x_seq, W_x, b_h, out);

    recurrence_mw<<<B_SZ * NW, 256, 0, stream>>>(h_tape, h_work, W_h, W_write, out);
}